// Round 6
// baseline (103.805 us; speedup 1.0000x reference)
//
#include <hip/hip_runtime.h>

// Tree-structured parent-child attention. B=8, N=2048, H=16, D=64, fp32.
// 16 heads x 16 lanes per node; each lane owns a float4 of the D=64 row.
//
// R6: same structural software pipeline as R5, compile fix only
// (__builtin_nontemporal_store needs a clang native vector type, not
// HIP_vector_type<float,4> -> go through ext_vector_type(4) alias).
//
// Structure: persistent block processes 8 nodes with a modulo-2 rotating
// register buffer: prologue loads nodes 0,1; body issues loads for k+2,
// fences (loads can't sink below a may-write asm), then computes node k.
// Both 28-reg buffers are structurally live -> scheduler cannot collapse
// back to the R1-R4 two-phase order. Output via non-temporal store (the
// 64 MiB output is never re-read; keep it out of L2/L3 so inputs stay).

#define D_DIM   64
#define H_DIM   16
#define N_NODES 2048   // parents per batch
#define ITERS   8      // nodes per block

typedef float f32x4 __attribute__((ext_vector_type(4)));

struct Frag { float4 q, kp, kc0, kc1, vp, vc0, vc1; };

__device__ __forceinline__ void issue_loads(
    Frag& f,
    const float* __restrict__ Qp, const float* __restrict__ Kp,
    const float* __restrict__ Vp, const float* __restrict__ Kc,
    const float* __restrict__ Vc,
    int bn, int h, int off)
{
    const int b = bn >> 11;           // N=2048
    const int n = bn & (N_NODES - 1);
    const size_t rowP  = ((size_t)bn * H_DIM + h) * D_DIM + off;
    const size_t rowC0 = (((size_t)b * 2 * N_NODES + 2 * n) * H_DIM + h) * D_DIM + off;
    const size_t rowC1 = rowC0 + (size_t)H_DIM * D_DIM;

    f.q   = *(const float4*)(Qp + rowP);
    f.kp  = *(const float4*)(Kp + rowP);
    f.kc0 = *(const float4*)(Kc + rowC0);
    f.kc1 = *(const float4*)(Kc + rowC1);
    f.vp  = *(const float4*)(Vp + rowP);
    f.vc0 = *(const float4*)(Vc + rowC0);
    f.vc1 = *(const float4*)(Vc + rowC1);
}

__device__ __forceinline__ void compute_node(
    const Frag& f, float* __restrict__ out, int bn, int h, int off)
{
    float s0 = f.q.x * f.kp.x  + f.q.y * f.kp.y  + f.q.z * f.kp.z  + f.q.w * f.kp.w;
    float s1 = f.q.x * f.kc0.x + f.q.y * f.kc0.y + f.q.z * f.kc0.z + f.q.w * f.kc0.w;
    float s2 = f.q.x * f.kc1.x + f.q.y * f.kc1.y + f.q.z * f.kc1.z + f.q.w * f.kc1.w;

    #pragma unroll
    for (int m = 8; m >= 1; m >>= 1) {
        s0 += __shfl_xor(s0, m);
        s1 += __shfl_xor(s1, m);
        s2 += __shfl_xor(s2, m);
    }

    const float scale = 0.125f;  // 1/sqrt(64)
    s0 *= scale; s1 *= scale; s2 *= scale;

    const float mx = fmaxf(s0, fmaxf(s1, s2));
    const float e0 = __expf(s0 - mx);
    const float e1 = __expf(s1 - mx);
    const float e2 = __expf(s2 - mx);
    const float inv = 1.0f / (e0 + e1 + e2 + 1e-9f);
    const float w0 = e0 * inv, w1 = e1 * inv, w2 = e2 * inv;

    f32x4 o;
    o.x = w0 * f.vp.x + w1 * f.vc0.x + w2 * f.vc1.x;
    o.y = w0 * f.vp.y + w1 * f.vc0.y + w2 * f.vc1.y;
    o.z = w0 * f.vp.z + w1 * f.vc0.z + w2 * f.vc1.z;
    o.w = w0 * f.vp.w + w1 * f.vc0.w + w2 * f.vc1.w;

    const size_t rowP = ((size_t)bn * H_DIM + h) * D_DIM + off;
    __builtin_nontemporal_store(o, (f32x4*)(out + rowP));
}

__global__ __launch_bounds__(256) void tree_attn_kernel(
    const float* __restrict__ Qp,
    const float* __restrict__ Kp,
    const float* __restrict__ Vp,
    const float* __restrict__ Kc,
    const float* __restrict__ Vc,
    float* __restrict__ out)
{
    const int h    = threadIdx.x >> 4;   // 0..15
    const int lane = threadIdx.x & 15;   // 0..15
    const int off  = lane * 4;
    const int base = blockIdx.x * ITERS; // 8 consecutive (b,n) nodes

    Frag A, B;
    issue_loads(A, Qp, Kp, Vp, Kc, Vc, base + 0, h, off);
    issue_loads(B, Qp, Kp, Vp, Kc, Vc, base + 1, h, off);
    asm volatile("" ::: "memory");  // both prologue bursts issue here

    #pragma unroll
    for (int k = 0; k < ITERS; ++k) {
        Frag& cur = (k & 1) ? B : A;          // static after full unroll
        if (k + 2 < ITERS) {
            Frag nxt;
            issue_loads(nxt, Qp, Kp, Vp, Kc, Vc, base + k + 2, h, off);
            asm volatile("" ::: "memory");    // loads may not sink below this
            compute_node(cur, out, base + k, h, off);
            cur = nxt;                        // rotate into the freed slot
        } else {
            compute_node(cur, out, base + k, h, off);
        }
    }
}

extern "C" void kernel_launch(void* const* d_in, const int* in_sizes, int n_in,
                              void* d_out, int out_size, void* d_ws, size_t ws_size,
                              hipStream_t stream) {
    (void)n_in; (void)d_ws; (void)ws_size; (void)out_size; (void)in_sizes;

    const float* Qp = (const float*)d_in[0];
    const float* Kp = (const float*)d_in[1];
    const float* Vp = (const float*)d_in[2];
    const float* Kc = (const float*)d_in[3];
    const float* Vc = (const float*)d_in[4];
    float* out = (float*)d_out;

    const int B = 8;
    dim3 grid((B * N_NODES) / ITERS);   // 2048 blocks
    dim3 block(256);                    // 16 heads x 16 lanes
    tree_attn_kernel<<<grid, block, 0, stream>>>(Qp, Kp, Vp, Kc, Vc, out);
}

// Round 7
// 94.199 us; speedup vs baseline: 1.1020x; 1.1020x over previous
//
#include <hip/hip_runtime.h>

// Tree-structured parent-child attention. B=8, N=2048, H=16, D=64, fp32.
// 16 heads x 16 lanes; each lane owns a float4 (16B) of the D=64 row.
//
// R7: 2x memory-level parallelism probe. R1/R4/R6 gave three different
// schedules (VGPR 20 vs 36, occ 78 vs 60, VALUBusy 11 vs 5.7) at IDENTICAL
// 103.5+-0.5 us -> schedule-invariant. Last open hypothesis: outstanding
// bytes per wave too low. Here each thread handles TWO nodes at once:
// 14 float4 loads in one burst (224B/lane in flight), interleaved compute.
// If dur doesn't move, the ~5.2 TB/s combined L3+HBM delivery rate is the
// pattern roofline and we stop.

#define D_DIM   64
#define H_DIM   16
#define N_NODES 2048

typedef float f32x4 __attribute__((ext_vector_type(4)));

__device__ __forceinline__ float dot4(const float4& a, const float4& b) {
    return a.x * b.x + a.y * b.y + a.z * b.z + a.w * b.w;
}

__global__ __launch_bounds__(256) void tree_attn_kernel(
    const float* __restrict__ Qp,
    const float* __restrict__ Kp,
    const float* __restrict__ Vp,
    const float* __restrict__ Kc,
    const float* __restrict__ Vc,
    float* __restrict__ out)
{
    const int h    = threadIdx.x >> 4;   // 0..15
    const int lane = threadIdx.x & 15;   // 0..15
    const int off  = lane * 4;

    // Two consecutive nodes per block; pairs never cross a batch (N even).
    const int bn0 = blockIdx.x * 2;
    const int bn1 = bn0 + 1;
    const int b   = bn0 >> 11;                 // / N_NODES
    const int n0  = bn0 & (N_NODES - 1);

    const size_t rowP0  = ((size_t)bn0 * H_DIM + h) * D_DIM + off;
    const size_t rowP1  = rowP0 + (size_t)H_DIM * D_DIM;
    const size_t rowC00 = (((size_t)b * 2 * N_NODES + 2 * n0) * H_DIM + h) * D_DIM + off;
    const size_t rowC01 = rowC00 + (size_t)H_DIM * D_DIM;      // child 1 of node 0
    const size_t rowC10 = rowC01 + (size_t)H_DIM * D_DIM;      // child 0 of node 1
    const size_t rowC11 = rowC10 + (size_t)H_DIM * D_DIM;      // child 1 of node 1

    // ---- 14-load burst: 224B/lane outstanding ----
    float4 qa   = *(const float4*)(Qp + rowP0);
    float4 qb   = *(const float4*)(Qp + rowP1);
    float4 kpa  = *(const float4*)(Kp + rowP0);
    float4 kpb  = *(const float4*)(Kp + rowP1);
    float4 kc0a = *(const float4*)(Kc + rowC00);
    float4 kc1a = *(const float4*)(Kc + rowC01);
    float4 kc0b = *(const float4*)(Kc + rowC10);
    float4 kc1b = *(const float4*)(Kc + rowC11);
    float4 vpa  = *(const float4*)(Vp + rowP0);
    float4 vpb  = *(const float4*)(Vp + rowP1);
    float4 vc0a = *(const float4*)(Vc + rowC00);
    float4 vc1a = *(const float4*)(Vc + rowC01);
    float4 vc0b = *(const float4*)(Vc + rowC10);
    float4 vc1b = *(const float4*)(Vc + rowC11);

    asm volatile("" ::: "memory");   // no load may sink below this point

    float s0a = dot4(qa, kpa),  s0b = dot4(qb, kpb);
    float s1a = dot4(qa, kc0a), s1b = dot4(qb, kc0b);
    float s2a = dot4(qa, kc1a), s2b = dot4(qb, kc1b);

    // 16-lane group reduction, two nodes interleaved (2x ILP in the chain).
    #pragma unroll
    for (int m = 8; m >= 1; m >>= 1) {
        s0a += __shfl_xor(s0a, m);  s0b += __shfl_xor(s0b, m);
        s1a += __shfl_xor(s1a, m);  s1b += __shfl_xor(s1b, m);
        s2a += __shfl_xor(s2a, m);  s2b += __shfl_xor(s2b, m);
    }

    const float scale = 0.125f;  // 1/sqrt(64)
    s0a *= scale; s1a *= scale; s2a *= scale;
    s0b *= scale; s1b *= scale; s2b *= scale;

    const float mxa = fmaxf(s0a, fmaxf(s1a, s2a));
    const float mxb = fmaxf(s0b, fmaxf(s1b, s2b));
    const float e0a = __expf(s0a - mxa), e0b = __expf(s0b - mxb);
    const float e1a = __expf(s1a - mxa), e1b = __expf(s1b - mxb);
    const float e2a = __expf(s2a - mxa), e2b = __expf(s2b - mxb);
    const float inva = 1.0f / (e0a + e1a + e2a + 1e-9f);
    const float invb = 1.0f / (e0b + e1b + e2b + 1e-9f);
    const float w0a = e0a * inva, w1a = e1a * inva, w2a = e2a * inva;
    const float w0b = e0b * invb, w1b = e1b * invb, w2b = e2b * invb;

    f32x4 oa, ob;
    oa.x = w0a * vpa.x + w1a * vc0a.x + w2a * vc1a.x;
    ob.x = w0b * vpb.x + w1b * vc0b.x + w2b * vc1b.x;
    oa.y = w0a * vpa.y + w1a * vc0a.y + w2a * vc1a.y;
    ob.y = w0b * vpb.y + w1b * vc0b.y + w2b * vc1b.y;
    oa.z = w0a * vpa.z + w1a * vc0a.z + w2a * vc1a.z;
    ob.z = w0b * vpb.z + w1b * vc0b.z + w2b * vc1b.z;
    oa.w = w0a * vpa.w + w1a * vc0a.w + w2a * vc1a.w;
    ob.w = w0b * vpb.w + w1b * vc0b.w + w2b * vc1b.w;

    __builtin_nontemporal_store(oa, (f32x4*)(out + rowP0));
    __builtin_nontemporal_store(ob, (f32x4*)(out + rowP1));
}

extern "C" void kernel_launch(void* const* d_in, const int* in_sizes, int n_in,
                              void* d_out, int out_size, void* d_ws, size_t ws_size,
                              hipStream_t stream) {
    (void)n_in; (void)d_ws; (void)ws_size; (void)out_size; (void)in_sizes;

    const float* Qp = (const float*)d_in[0];
    const float* Kp = (const float*)d_in[1];
    const float* Vp = (const float*)d_in[2];
    const float* Kc = (const float*)d_in[3];
    const float* Vc = (const float*)d_in[4];
    float* out = (float*)d_out;

    const int B = 8;
    dim3 grid((B * N_NODES) / 2);   // 8192 blocks, 2 nodes each
    dim3 block(256);                // 16 heads x 16 lanes
    tree_attn_kernel<<<grid, block, 0, stream>>>(Qp, Kp, Vp, Kc, Vc, out);
}